// Round 1
// baseline (3334.583 us; speedup 1.0000x reference)
//
#include <hip/hip_runtime.h>
#include <hip/hip_bf16.h>
#include <math.h>

#define B 4
#define S 2048
#define H 768
#define V 32000
#define HID 100
#define G4 400   // 4*HID
#define M_TOT (B*S)

__device__ __forceinline__ float sigmoidf_(float x) {
  return 1.0f / (1.0f + __expf(-x));
}
__device__ __forceinline__ float tanhf_(float x) {
  float ax = fabsf(x);
  float e = __expf(-2.0f * ax);
  float t = (1.0f - e) / (1.0f + e);
  return copysignf(t, x);
}

// ---------------- Kernel 1: surprisal (online softmax + gather) --------------
__global__ __launch_bounds__(256) void surprisal_kernel(
    const float* __restrict__ logits, const int* __restrict__ ids,
    const float* __restrict__ mask, float* __restrict__ surp) {
  int row = blockIdx.x;
  const float* x = logits + (size_t)row * V;
  int tid = threadIdx.x;
  float m = -INFINITY, s = 0.0f;
  const float4* x4 = (const float4*)x;
  for (int i = tid; i < V / 4; i += 256) {
    float4 v = x4[i];
    float mv = fmaxf(fmaxf(v.x, v.y), fmaxf(v.z, v.w));
    if (mv > m) { s *= __expf(m - mv); m = mv; }
    s += __expf(v.x - m) + __expf(v.y - m) + __expf(v.z - m) + __expf(v.w - m);
  }
  #pragma unroll
  for (int off = 32; off > 0; off >>= 1) {
    float mo = __shfl_xor(m, off);
    float so = __shfl_xor(s, off);
    float mn = fmaxf(m, mo);
    s = s * __expf(m - mn) + so * __expf(mo - mn);
    m = mn;
  }
  __shared__ float sm[4], ss[4];
  int wid = tid >> 6, lane = tid & 63;
  if (lane == 0) { sm[wid] = m; ss[wid] = s; }
  __syncthreads();
  if (tid == 0) {
    float M = sm[0], Ssum = ss[0];
    #pragma unroll
    for (int w = 1; w < 4; ++w) {
      float mo = sm[w], so = ss[w];
      float mn = fmaxf(M, mo);
      Ssum = Ssum * __expf(M - mn) + so * __expf(mo - mn);
      M = mn;
    }
    float xid = x[ids[row]];
    // surp = (lse - x_id)/ln2 * mask
    surp[row] = (M + __logf(Ssum) - xid) * 1.4426950408889634f * mask[row];
  }
}

// ---------------- Kernel 2: x_proj = [hs|surp] @ W_ih^T + b_ih + b_hh --------
#define BM 64
#define BN 64
#define BK 32

__global__ __launch_bounds__(256) void xproj_kernel(
    const float* __restrict__ A,     // hidden_states [M,768]
    const float* __restrict__ surp,  // [M]
    const float* __restrict__ W,     // W_ih [400,769]
    const float* __restrict__ b_ih, const float* __restrict__ b_hh,
    float* __restrict__ xproj) {     // [M,400]
  __shared__ float As[BK][BM];
  __shared__ float Bs[BK][BN];
  int tid = threadIdx.x;
  int m0 = blockIdx.x * BM;
  int n0 = blockIdx.y * BN;
  int tx = tid & 15, ty = tid >> 4;
  float acc[4][4] = {};
  for (int k0 = 0; k0 < H; k0 += BK) {
    #pragma unroll
    for (int l = 0; l < 2; ++l) {
      int idx = tid + l * 256;        // 0..511
      int row = idx >> 3;
      int kq = idx & 7;
      float4 v = *(const float4*)&A[(size_t)(m0 + row) * H + k0 + kq * 4];
      As[kq * 4 + 0][row] = v.x;
      As[kq * 4 + 1][row] = v.y;
      As[kq * 4 + 2][row] = v.z;
      As[kq * 4 + 3][row] = v.w;
    }
    #pragma unroll
    for (int l = 0; l < 8; ++l) {
      int idx = tid + l * 256;        // 0..2047
      int n = idx >> 5;
      int kk = idx & 31;
      int gn = n0 + n;
      Bs[kk][n] = (gn < G4) ? W[(size_t)gn * (H + 1) + k0 + kk] : 0.0f;
    }
    __syncthreads();
    #pragma unroll
    for (int k = 0; k < BK; ++k) {
      float4 a = *(const float4*)&As[k][ty * 4];
      float4 bq = *(const float4*)&Bs[k][tx * 4];
      float av[4] = {a.x, a.y, a.z, a.w};
      float bv[4] = {bq.x, bq.y, bq.z, bq.w};
      #pragma unroll
      for (int i = 0; i < 4; ++i)
        #pragma unroll
        for (int j = 0; j < 4; ++j)
          acc[i][j] += av[i] * bv[j];
    }
    __syncthreads();
  }
  #pragma unroll
  for (int i = 0; i < 4; ++i) {
    int gm = m0 + ty * 4 + i;
    float sv = surp[gm];
    #pragma unroll
    for (int j = 0; j < 4; ++j) {
      int gn = n0 + tx * 4 + j;
      if (gn < G4) {
        float val = acc[i][j] + sv * W[(size_t)gn * (H + 1) + H] + b_ih[gn] + b_hh[gn];
        xproj[(size_t)gm * G4 + gn] = val;
      }
    }
  }
}

// ---------------- Kernel 3: LSTM scan + classifier ---------------------------
__global__ __launch_bounds__(512) void lstm_kernel(
    const float* __restrict__ xproj,  // [B,S,400]
    const float* __restrict__ W_hh,   // [400,100]
    const float* __restrict__ sent,   // [B,3]
    const float* __restrict__ cls_W,  // [3,103]
    const float* __restrict__ cls_b,  // [3]
    float* __restrict__ out) {        // [B,3]
  int b = blockIdx.x;
  int tid = threadIdx.x;
  __shared__ float h_s[HID];
  __shared__ float gates_s[G4];
  float w[HID];
  if (tid < G4) {
    #pragma unroll
    for (int j = 0; j < HID; ++j) w[j] = W_hh[tid * HID + j];
  }
  float c_reg = 0.0f;
  if (tid < HID) h_s[tid] = 0.0f;
  __syncthreads();
  const float* xp = xproj + (size_t)b * S * G4;
  for (int t = 0; t < S; ++t) {
    if (tid < G4) {
      float xv = xp[t * G4 + tid];
      float a0 = 0.f, a1 = 0.f, a2 = 0.f, a3 = 0.f;
      #pragma unroll
      for (int j = 0; j < HID; j += 4) {
        a0 += w[j]     * h_s[j];
        a1 += w[j + 1] * h_s[j + 1];
        a2 += w[j + 2] * h_s[j + 2];
        a3 += w[j + 3] * h_s[j + 3];
      }
      gates_s[tid] = (a0 + a1) + (a2 + a3) + xv;
    }
    __syncthreads();
    if (tid < HID) {
      float ig = sigmoidf_(gates_s[tid]);
      float fg = sigmoidf_(gates_s[HID + tid]);
      float gg = tanhf_(gates_s[2 * HID + tid]);
      float og = sigmoidf_(gates_s[3 * HID + tid]);
      c_reg = fg * c_reg + ig * gg;
      h_s[tid] = og * tanhf_(c_reg);
    }
    __syncthreads();
  }
  if (tid < 3) {
    float acc = cls_b[tid];
    const float* cw = cls_W + tid * (HID + 3);
    #pragma unroll
    for (int j = 0; j < HID; ++j) acc += cw[j] * h_s[j];
    #pragma unroll
    for (int k2 = 0; k2 < 3; ++k2) acc += cw[HID + k2] * sent[b * 3 + k2];
    out[b * 3 + tid] = acc;
  }
}

extern "C" void kernel_launch(void* const* d_in, const int* in_sizes, int n_in,
                              void* d_out, int out_size, void* d_ws, size_t ws_size,
                              hipStream_t stream) {
  const int*   input_ids = (const int*)d_in[0];
  const float* mask      = (const float*)d_in[1];
  const float* sent      = (const float*)d_in[2];
  const float* hs        = (const float*)d_in[3];
  const float* logits    = (const float*)d_in[4];
  const float* W_ih      = (const float*)d_in[5];
  const float* W_hh      = (const float*)d_in[6];
  const float* b_ih      = (const float*)d_in[7];
  const float* b_hh      = (const float*)d_in[8];
  const float* cls_W     = (const float*)d_in[9];
  const float* cls_b     = (const float*)d_in[10];
  float* out = (float*)d_out;

  float* surp  = (float*)d_ws;            // M_TOT floats
  float* xproj = surp + M_TOT;            // M_TOT*400 floats

  surprisal_kernel<<<M_TOT, 256, 0, stream>>>(logits, input_ids, mask, surp);
  xproj_kernel<<<dim3(M_TOT / BM, (G4 + BN - 1) / BN), 256, 0, stream>>>(
      hs, surp, W_ih, b_ih, b_hh, xproj);
  lstm_kernel<<<B, 512, 0, stream>>>(xproj, W_hh, sent, cls_W, cls_b, out);
}

// Round 2
// 2712.037 us; speedup vs baseline: 1.2295x; 1.2295x over previous
//
#include <hip/hip_runtime.h>
#include <hip/hip_bf16.h>
#include <math.h>

#define B 4
#define S 2048
#define H 768
#define V 32000
#define HID 100
#define G4 400   // 4*HID
#define M_TOT (B*S)

__device__ __forceinline__ float sigmoidf_(float x) {
  return 1.0f / (1.0f + __expf(-x));
}
__device__ __forceinline__ float tanhf_(float x) {
  float ax = fabsf(x);
  float e = __expf(-2.0f * ax);
  float t = (1.0f - e) / (1.0f + e);
  return copysignf(t, x);
}

// ---------------- Kernel 1: surprisal (online softmax + gather) --------------
__global__ __launch_bounds__(256) void surprisal_kernel(
    const float* __restrict__ logits, const int* __restrict__ ids,
    const float* __restrict__ mask, float* __restrict__ surp) {
  int row = blockIdx.x;
  const float* x = logits + (size_t)row * V;
  int tid = threadIdx.x;
  float m = -INFINITY, s = 0.0f;
  const float4* x4 = (const float4*)x;
  for (int i = tid; i < V / 4; i += 256) {
    float4 v = x4[i];
    float mv = fmaxf(fmaxf(v.x, v.y), fmaxf(v.z, v.w));
    if (mv > m) { s *= __expf(m - mv); m = mv; }
    s += __expf(v.x - m) + __expf(v.y - m) + __expf(v.z - m) + __expf(v.w - m);
  }
  #pragma unroll
  for (int off = 32; off > 0; off >>= 1) {
    float mo = __shfl_xor(m, off);
    float so = __shfl_xor(s, off);
    float mn = fmaxf(m, mo);
    s = s * __expf(m - mn) + so * __expf(mo - mn);
    m = mn;
  }
  __shared__ float sm[4], ss[4];
  int wid = tid >> 6, lane = tid & 63;
  if (lane == 0) { sm[wid] = m; ss[wid] = s; }
  __syncthreads();
  if (tid == 0) {
    float M = sm[0], Ssum = ss[0];
    #pragma unroll
    for (int w = 1; w < 4; ++w) {
      float mo = sm[w], so = ss[w];
      float mn = fmaxf(M, mo);
      Ssum = Ssum * __expf(M - mn) + so * __expf(mo - mn);
      M = mn;
    }
    float xid = x[ids[row]];
    // surp = (lse - x_id)/ln2 * mask
    surp[row] = (M + __logf(Ssum) - xid) * 1.4426950408889634f * mask[row];
  }
}

// ---------------- Kernel 2: x_proj = [hs|surp] @ W_ih^T + b_ih + b_hh --------
#define BM 64
#define BN 64
#define BK 32

__global__ __launch_bounds__(256) void xproj_kernel(
    const float* __restrict__ A,     // hidden_states [M,768]
    const float* __restrict__ surp,  // [M]
    const float* __restrict__ W,     // W_ih [400,769]
    const float* __restrict__ b_ih, const float* __restrict__ b_hh,
    float* __restrict__ xproj) {     // [M,400]
  __shared__ float As[BK][BM];
  __shared__ float Bs[BK][BN];
  int tid = threadIdx.x;
  int m0 = blockIdx.x * BM;
  int n0 = blockIdx.y * BN;
  int tx = tid & 15, ty = tid >> 4;
  float acc[4][4] = {};
  for (int k0 = 0; k0 < H; k0 += BK) {
    #pragma unroll
    for (int l = 0; l < 2; ++l) {
      int idx = tid + l * 256;        // 0..511
      int row = idx >> 3;
      int kq = idx & 7;
      float4 v = *(const float4*)&A[(size_t)(m0 + row) * H + k0 + kq * 4];
      As[kq * 4 + 0][row] = v.x;
      As[kq * 4 + 1][row] = v.y;
      As[kq * 4 + 2][row] = v.z;
      As[kq * 4 + 3][row] = v.w;
    }
    #pragma unroll
    for (int l = 0; l < 8; ++l) {
      int idx = tid + l * 256;        // 0..2047
      int n = idx >> 5;
      int kk = idx & 31;
      int gn = n0 + n;
      Bs[kk][n] = (gn < G4) ? W[(size_t)gn * (H + 1) + k0 + kk] : 0.0f;
    }
    __syncthreads();
    #pragma unroll
    for (int k = 0; k < BK; ++k) {
      float4 a = *(const float4*)&As[k][ty * 4];
      float4 bq = *(const float4*)&Bs[k][tx * 4];
      float av[4] = {a.x, a.y, a.z, a.w};
      float bv[4] = {bq.x, bq.y, bq.z, bq.w};
      #pragma unroll
      for (int i = 0; i < 4; ++i)
        #pragma unroll
        for (int j = 0; j < 4; ++j)
          acc[i][j] += av[i] * bv[j];
    }
    __syncthreads();
  }
  #pragma unroll
  for (int i = 0; i < 4; ++i) {
    int gm = m0 + ty * 4 + i;
    float sv = surp[gm];
    #pragma unroll
    for (int j = 0; j < 4; ++j) {
      int gn = n0 + tx * 4 + j;
      if (gn < G4) {
        float val = acc[i][j] + sv * W[(size_t)gn * (H + 1) + H] + b_ih[gn] + b_hh[gn];
        xproj[(size_t)gm * G4 + gn] = val;
      }
    }
  }
}

// ---------------- Kernel 3: LSTM scan + classifier ---------------------------
// 448 threads = 7 waves; threads 0..399 each own one gate row of W_hh (100
// fp32 weights held in REGISTERS — launch_bounds(448,2) gives a 256-VGPR
// budget so no scratch spill). h broadcast from LDS via float4 (25
// ds_read_b128 per step instead of 100 ds_read_b32). xproj prefetched one
// step ahead.
__global__ __launch_bounds__(448, 2) void lstm_kernel(
    const float* __restrict__ xproj,  // [B,S,400]
    const float* __restrict__ W_hh,   // [400,100]
    const float* __restrict__ sent,   // [B,3]
    const float* __restrict__ cls_W,  // [3,103]
    const float* __restrict__ cls_b,  // [3]
    float* __restrict__ out) {        // [B,3]
  int b = blockIdx.x;
  int tid = threadIdx.x;
  __shared__ __align__(16) float h_s[HID];
  __shared__ float gates_s[G4];
  float w[HID];
  if (tid < G4) {
    const float4* wr = (const float4*)(W_hh + (size_t)tid * HID);
    #pragma unroll
    for (int j = 0; j < HID / 4; ++j) {
      float4 v = wr[j];
      w[4 * j + 0] = v.x;
      w[4 * j + 1] = v.y;
      w[4 * j + 2] = v.z;
      w[4 * j + 3] = v.w;
    }
  }
  float c_reg = 0.0f;
  if (tid < HID) h_s[tid] = 0.0f;
  __syncthreads();

  const float* xp = xproj + (size_t)b * S * G4;
  float xv = (tid < G4) ? xp[tid] : 0.0f;

  for (int t = 0; t < S; ++t) {
    // prefetch next step's xproj value (independent of h) to hide HBM latency
    int tn = (t + 1 < S) ? (t + 1) : t;
    float xv_next = (tid < G4) ? xp[(size_t)tn * G4 + tid] : 0.0f;

    if (tid < G4) {
      float a0 = 0.f, a1 = 0.f, a2 = 0.f, a3 = 0.f;
      const float4* h4 = (const float4*)h_s;
      #pragma unroll
      for (int j = 0; j < HID / 4; ++j) {
        float4 hv = h4[j];   // uniform address -> LDS broadcast
        a0 += w[4 * j + 0] * hv.x;
        a1 += w[4 * j + 1] * hv.y;
        a2 += w[4 * j + 2] * hv.z;
        a3 += w[4 * j + 3] * hv.w;
      }
      gates_s[tid] = (a0 + a1) + (a2 + a3) + xv;
    }
    __syncthreads();
    if (tid < HID) {
      float ig = sigmoidf_(gates_s[tid]);
      float fg = sigmoidf_(gates_s[HID + tid]);
      float gg = tanhf_(gates_s[2 * HID + tid]);
      float og = sigmoidf_(gates_s[3 * HID + tid]);
      c_reg = fg * c_reg + ig * gg;
      h_s[tid] = og * tanhf_(c_reg);
    }
    xv = xv_next;
    __syncthreads();
  }

  if (tid < 3) {
    float acc = cls_b[tid];
    const float* cw = cls_W + tid * (HID + 3);
    #pragma unroll
    for (int j = 0; j < HID; ++j) acc += cw[j] * h_s[j];
    #pragma unroll
    for (int k2 = 0; k2 < 3; ++k2) acc += cw[HID + k2] * sent[b * 3 + k2];
    out[b * 3 + tid] = acc;
  }
}

extern "C" void kernel_launch(void* const* d_in, const int* in_sizes, int n_in,
                              void* d_out, int out_size, void* d_ws, size_t ws_size,
                              hipStream_t stream) {
  const int*   input_ids = (const int*)d_in[0];
  const float* mask      = (const float*)d_in[1];
  const float* sent      = (const float*)d_in[2];
  const float* hs        = (const float*)d_in[3];
  const float* logits    = (const float*)d_in[4];
  const float* W_ih      = (const float*)d_in[5];
  const float* W_hh      = (const float*)d_in[6];
  const float* b_ih      = (const float*)d_in[7];
  const float* b_hh      = (const float*)d_in[8];
  const float* cls_W     = (const float*)d_in[9];
  const float* cls_b     = (const float*)d_in[10];
  float* out = (float*)d_out;

  float* surp  = (float*)d_ws;            // M_TOT floats
  float* xproj = surp + M_TOT;            // M_TOT*400 floats

  surprisal_kernel<<<M_TOT, 256, 0, stream>>>(logits, input_ids, mask, surp);
  xproj_kernel<<<dim3(M_TOT / BM, (G4 + BN - 1) / BN), 256, 0, stream>>>(
      hs, surp, W_ih, b_ih, b_hh, xproj);
  lstm_kernel<<<B, 448, 0, stream>>>(xproj, W_hh, sent, cls_W, cls_b, out);
}

// Round 3
// 1706.270 us; speedup vs baseline: 1.9543x; 1.5895x over previous
//
#include <hip/hip_runtime.h>
#include <hip/hip_bf16.h>
#include <math.h>

#define B 4
#define S 2048
#define H 768
#define V 32000
#define HID 100
#define G4 400   // 4*HID
#define M_TOT (B*S)

typedef _Float16 half2_t __attribute__((ext_vector_type(2)));
typedef _Float16 half8_t __attribute__((ext_vector_type(8)));

__device__ __forceinline__ float fdot2_(half2_t a, half2_t b, float c) {
#if __has_builtin(__builtin_amdgcn_fdot2)
  return __builtin_amdgcn_fdot2(a, b, c, false);
#else
  return c + (float)a[0] * (float)b[0] + (float)a[1] * (float)b[1];
#endif
}

__device__ __forceinline__ float sigmoidf_(float x) {
  return 1.0f / (1.0f + __expf(-x));
}
__device__ __forceinline__ float tanhf_(float x) {
  float ax = fabsf(x);
  float e = __expf(-2.0f * ax);
  float t = (1.0f - e) / (1.0f + e);
  return copysignf(t, x);
}

// ---------------- Kernel 1: surprisal (online softmax + gather) --------------
__global__ __launch_bounds__(256) void surprisal_kernel(
    const float* __restrict__ logits, const int* __restrict__ ids,
    const float* __restrict__ mask, float* __restrict__ surp) {
  int row = blockIdx.x;
  const float* x = logits + (size_t)row * V;
  int tid = threadIdx.x;
  float m = -INFINITY, s = 0.0f;
  const float4* x4 = (const float4*)x;
  for (int i = tid; i < V / 4; i += 256) {
    float4 v = x4[i];
    float mv = fmaxf(fmaxf(v.x, v.y), fmaxf(v.z, v.w));
    if (mv > m) { s *= __expf(m - mv); m = mv; }
    s += __expf(v.x - m) + __expf(v.y - m) + __expf(v.z - m) + __expf(v.w - m);
  }
  #pragma unroll
  for (int off = 32; off > 0; off >>= 1) {
    float mo = __shfl_xor(m, off);
    float so = __shfl_xor(s, off);
    float mn = fmaxf(m, mo);
    s = s * __expf(m - mn) + so * __expf(mo - mn);
    m = mn;
  }
  __shared__ float sm[4], ss[4];
  int wid = tid >> 6, lane = tid & 63;
  if (lane == 0) { sm[wid] = m; ss[wid] = s; }
  __syncthreads();
  if (tid == 0) {
    float M = sm[0], Ssum = ss[0];
    #pragma unroll
    for (int w = 1; w < 4; ++w) {
      float mo = sm[w], so = ss[w];
      float mn = fmaxf(M, mo);
      Ssum = Ssum * __expf(M - mn) + so * __expf(mo - mn);
      M = mn;
    }
    float xid = x[ids[row]];
    surp[row] = (M + __logf(Ssum) - xid) * 1.4426950408889634f * mask[row];
  }
}

// ---------------- Kernel 2: x_proj = [hs|surp] @ W_ih^T + b_ih + b_hh --------
#define BM 64
#define BN 64
#define BK 32

__global__ __launch_bounds__(256) void xproj_kernel(
    const float* __restrict__ A,     // hidden_states [M,768]
    const float* __restrict__ surp,  // [M]
    const float* __restrict__ W,     // W_ih [400,769]
    const float* __restrict__ b_ih, const float* __restrict__ b_hh,
    float* __restrict__ xproj) {     // [M,400]
  __shared__ float As[BK][BM];
  __shared__ float Bs[BK][BN];
  int tid = threadIdx.x;
  int m0 = blockIdx.x * BM;
  int n0 = blockIdx.y * BN;
  int tx = tid & 15, ty = tid >> 4;
  float acc[4][4] = {};
  for (int k0 = 0; k0 < H; k0 += BK) {
    #pragma unroll
    for (int l = 0; l < 2; ++l) {
      int idx = tid + l * 256;        // 0..511
      int row = idx >> 3;
      int kq = idx & 7;
      float4 v = *(const float4*)&A[(size_t)(m0 + row) * H + k0 + kq * 4];
      As[kq * 4 + 0][row] = v.x;
      As[kq * 4 + 1][row] = v.y;
      As[kq * 4 + 2][row] = v.z;
      As[kq * 4 + 3][row] = v.w;
    }
    #pragma unroll
    for (int l = 0; l < 8; ++l) {
      int idx = tid + l * 256;        // 0..2047
      int n = idx >> 5;
      int kk = idx & 31;
      int gn = n0 + n;
      Bs[kk][n] = (gn < G4) ? W[(size_t)gn * (H + 1) + k0 + kk] : 0.0f;
    }
    __syncthreads();
    #pragma unroll
    for (int k = 0; k < BK; ++k) {
      float4 a = *(const float4*)&As[k][ty * 4];
      float4 bq = *(const float4*)&Bs[k][tx * 4];
      float av[4] = {a.x, a.y, a.z, a.w};
      float bv[4] = {bq.x, bq.y, bq.z, bq.w};
      #pragma unroll
      for (int i = 0; i < 4; ++i)
        #pragma unroll
        for (int j = 0; j < 4; ++j)
          acc[i][j] += av[i] * bv[j];
    }
    __syncthreads();
  }
  #pragma unroll
  for (int i = 0; i < 4; ++i) {
    int gm = m0 + ty * 4 + i;
    float sv = surp[gm];
    #pragma unroll
    for (int j = 0; j < 4; ++j) {
      int gn = n0 + tx * 4 + j;
      if (gn < G4) {
        float val = acc[i][j] + sv * W[(size_t)gn * (H + 1) + H] + b_ih[gn] + b_hh[gn];
        xproj[(size_t)gm * G4 + gn] = val;
      }
    }
  }
}

// ---------------- Kernel 3: LSTM scan + classifier ---------------------------
// 256 threads = 4 waves (1/SIMD, balanced). Threads 0..199 each own TWO gate
// rows (2i, 2i+1): weights held as packed half2 in registers (104 VGPRs),
// h broadcast from LDS as f16 (13 ds_read_b128 per thread per step, half the
// bytes of fp32, reused across 2 rows -> 3.4x less LDS return traffic than
// round-1). Dot products via v_dot2_f32_f16 (fp32 accumulate). c/h update in
// fp32; h stored f16 (quantization ~5e-4, threshold 7e-3).
#define NH2 52          // 50 half2 + 2 zero-pad -> 13 x b128
__global__ __launch_bounds__(256, 1) void lstm_kernel(
    const float* __restrict__ xproj,  // [B,S,400]
    const float* __restrict__ W_hh,   // [400,100]
    const float* __restrict__ sent,   // [B,3]
    const float* __restrict__ cls_W,  // [3,103]
    const float* __restrict__ cls_b,  // [3]
    float* __restrict__ out) {        // [B,3]
  int b = blockIdx.x;
  int tid = threadIdx.x;
  __shared__ __align__(16) _Float16 h_s[2 * NH2];   // 104 halves
  __shared__ float gates_s[G4];

  half2_t w0[NH2], w1[NH2];
  int r0 = 2 * tid, r1 = 2 * tid + 1;
  if (tid < 200) {
    const float* wr0 = W_hh + (size_t)r0 * HID;
    const float* wr1 = W_hh + (size_t)r1 * HID;
    #pragma unroll
    for (int j = 0; j < 50; ++j) {
      w0[j] = half2_t{(_Float16)wr0[2 * j], (_Float16)wr0[2 * j + 1]};
      w1[j] = half2_t{(_Float16)wr1[2 * j], (_Float16)wr1[2 * j + 1]};
    }
    #pragma unroll
    for (int j = 50; j < NH2; ++j) { w0[j] = half2_t{0, 0}; w1[j] = half2_t{0, 0}; }
  }
  float c_reg = 0.0f;
  if (tid < 2 * NH2) h_s[tid] = (_Float16)0;
  __syncthreads();

  const float* xp = xproj + (size_t)b * S * G4;
  float2 xv = (tid < 200) ? ((const float2*)xp)[tid] : float2{0.f, 0.f};

  for (int t = 0; t < S; ++t) {
    int tn = (t + 1 < S) ? (t + 1) : t;
    float2 xv_next = (tid < 200) ? ((const float2*)(xp + (size_t)tn * G4))[tid]
                                 : float2{0.f, 0.f};

    if (tid < 200) {
      float a0 = 0.f, a1 = 0.f;
      const half8_t* h8 = (const half8_t*)h_s;
      #pragma unroll
      for (int j = 0; j < 13; ++j) {
        half8_t hv = h8[j];               // uniform address -> broadcast
        half2_t ha = {hv[0], hv[1]}, hb = {hv[2], hv[3]};
        half2_t hc = {hv[4], hv[5]}, hd = {hv[6], hv[7]};
        a0 = fdot2_(w0[4 * j + 0], ha, a0);
        a1 = fdot2_(w1[4 * j + 0], ha, a1);
        a0 = fdot2_(w0[4 * j + 1], hb, a0);
        a1 = fdot2_(w1[4 * j + 1], hb, a1);
        a0 = fdot2_(w0[4 * j + 2], hc, a0);
        a1 = fdot2_(w1[4 * j + 2], hc, a1);
        a0 = fdot2_(w0[4 * j + 3], hd, a0);
        a1 = fdot2_(w1[4 * j + 3], hd, a1);
      }
      *(float2*)&gates_s[r0] = float2{a0 + xv.x, a1 + xv.y};
    }
    __syncthreads();
    if (tid < HID) {
      float ig = sigmoidf_(gates_s[tid]);
      float fg = sigmoidf_(gates_s[HID + tid]);
      float gg = tanhf_(gates_s[2 * HID + tid]);
      float og = sigmoidf_(gates_s[3 * HID + tid]);
      c_reg = fg * c_reg + ig * gg;
      h_s[tid] = (_Float16)(og * tanhf_(c_reg));
    }
    xv = xv_next;
    __syncthreads();
  }

  if (tid < 3) {
    float acc = cls_b[tid];
    const float* cw = cls_W + tid * (HID + 3);
    #pragma unroll
    for (int j = 0; j < HID; ++j) acc += cw[j] * (float)h_s[j];
    #pragma unroll
    for (int k2 = 0; k2 < 3; ++k2) acc += cw[HID + k2] * sent[b * 3 + k2];
    out[b * 3 + tid] = acc;
  }
}

extern "C" void kernel_launch(void* const* d_in, const int* in_sizes, int n_in,
                              void* d_out, int out_size, void* d_ws, size_t ws_size,
                              hipStream_t stream) {
  const int*   input_ids = (const int*)d_in[0];
  const float* mask      = (const float*)d_in[1];
  const float* sent      = (const float*)d_in[2];
  const float* hs        = (const float*)d_in[3];
  const float* logits    = (const float*)d_in[4];
  const float* W_ih      = (const float*)d_in[5];
  const float* W_hh      = (const float*)d_in[6];
  const float* b_ih      = (const float*)d_in[7];
  const float* b_hh      = (const float*)d_in[8];
  const float* cls_W     = (const float*)d_in[9];
  const float* cls_b     = (const float*)d_in[10];
  float* out = (float*)d_out;

  float* surp  = (float*)d_ws;            // M_TOT floats
  float* xproj = surp + M_TOT;            // M_TOT*400 floats

  surprisal_kernel<<<M_TOT, 256, 0, stream>>>(logits, input_ids, mask, surp);
  xproj_kernel<<<dim3(M_TOT / BM, (G4 + BN - 1) / BN), 256, 0, stream>>>(
      hs, surp, W_ih, b_ih, b_hh, xproj);
  lstm_kernel<<<B, 256, 0, stream>>>(xproj, W_hh, sent, cls_W, cls_b, out);
}